// Round 7
// baseline (288.134 us; speedup 1.0000x reference)
//
#include <hip/hip_runtime.h>

typedef unsigned short u16;
typedef __attribute__((ext_vector_type(8))) short bf16x8;
typedef __attribute__((ext_vector_type(4))) float f32x4;

constexpr int CH = 64;      // IN_CH == HID == 64
constexpr int NG = 64;      // graphs
constexpr int NC = 10;      // classes
constexpr int SHIFT = 9;    // bucket = 512 nodes
constexpr int BW = 1 << SHIFT;
constexpr int EPW = 8192;   // edges per workgroup in bucket pass

__device__ __forceinline__ void f4add(float4& a, const float4 v) {
    a.x += v.x; a.y += v.y; a.z += v.z; a.w += v.w;
}
__device__ __forceinline__ u16 f2bf(float f) {   // RNE f32->bf16
    unsigned u = __float_as_uint(f);
    u = (u + 0x7FFFu + ((u >> 16) & 1u)) >> 16;
    return (u16)u;
}
__device__ __forceinline__ void bfacc(float4& a, unsigned lo, unsigned hi) {
    a.x += __uint_as_float(lo << 16);
    a.y += __uint_as_float(lo & 0xFFFF0000u);
    a.z += __uint_as_float(hi << 16);
    a.w += __uint_as_float(hi & 0xFFFF0000u);
}

// ---- B1: bin edges by dst bucket; packed record = src | (dstLocal<<17) ----
__global__ __launch_bounds__(256) void k_bucket(const int* __restrict__ src,
                                                const int* __restrict__ dst,
                                                int* __restrict__ bcnt,
                                                int* __restrict__ bbuf,
                                                int nb, int cap, int n_edges)
{
    __shared__ int hist[256];
    __shared__ int cur[256];
    int t = threadIdx.x;
    int e0 = blockIdx.x * EPW;
    int e1 = min(e0 + EPW, n_edges);
    if (t < nb) hist[t] = 0;
    __syncthreads();
    for (int e = e0 + t; e < e1; e += 256)
        atomicAdd(&hist[dst[e] >> SHIFT], 1);
    __syncthreads();
    if (t < nb) cur[t] = atomicAdd(&bcnt[t], hist[t]);   // reserve range
    __syncthreads();
    for (int e = e0 + t; e < e1; e += 256) {
        int d = dst[e];
        int b = d >> SHIFT;
        int pos = atomicAdd(&cur[b], 1);
        if (pos < cap)
            bbuf[(size_t)b * cap + pos] = src[e] | ((d & (BW - 1)) << 17);
    }
}

// ---- scan bucket counts -> bucket csr bases; also rowptr[n] ----------------
__global__ __launch_bounds__(256) void k_bscan(const int* __restrict__ bcnt,
                                               int* __restrict__ bbase,
                                               int* __restrict__ rowptr,
                                               int nb, int n, int cap)
{
    __shared__ int lds[256];
    int t = threadIdx.x;
    int v = (t < nb) ? min(bcnt[t], cap) : 0;
    lds[t] = v;
    __syncthreads();
    for (int off = 1; off < 256; off <<= 1) {
        int u = (t >= off) ? lds[t - off] : 0;
        __syncthreads();
        lds[t] += u;
        __syncthreads();
    }
    if (t < nb) bbase[t] = lds[t] - v;
    if (t == nb - 1) { bbase[nb] = lds[t]; rowptr[n] = lds[t]; }
}

// ---- B2: per-bucket local count + scan + place; contiguous csr window -----
__global__ __launch_bounds__(256) void k_build(const int* __restrict__ bbuf,
                                               const int* __restrict__ bcnt,
                                               const int* __restrict__ bbase,
                                               int* __restrict__ rowptr,
                                               int* __restrict__ csr,
                                               int cap, int n)
{
    __shared__ int hist[BW];
    __shared__ int cur[BW];
    __shared__ int psum[256];
    int b = blockIdx.x;
    int t = threadIdx.x;
    int cnt = min(bcnt[b], cap);
    int base = bbase[b];
    const int* mybuf = bbuf + (size_t)b * cap;
    hist[t] = 0; hist[t + 256] = 0;
    __syncthreads();
    for (int i = t; i < cnt; i += 256)
        atomicAdd(&hist[mybuf[i] >> 17], 1);
    __syncthreads();
    int h0 = hist[2 * t], h1 = hist[2 * t + 1];
    int ps = h0 + h1;
    psum[t] = ps;
    __syncthreads();
    for (int off = 1; off < 256; off <<= 1) {
        int u = (t >= off) ? psum[t - off] : 0;
        __syncthreads();
        psum[t] += u;
        __syncthreads();
    }
    int e0 = psum[t] - ps;                 // exclusive start of pair (2t,2t+1)
    int nodeBase = b * BW;
    cur[2 * t]     = base + e0;
    cur[2 * t + 1] = base + e0 + h0;
    if (nodeBase + 2 * t < n)     rowptr[nodeBase + 2 * t]     = base + e0;
    if (nodeBase + 2 * t + 1 < n) rowptr[nodeBase + 2 * t + 1] = base + e0 + h0;
    __syncthreads();
    for (int i = t; i < cnt; i += 256) {
        int v = mybuf[i];
        int pos = atomicAdd(&cur[v >> 17], 1);
        csr[pos] = v & 0x1FFFF;
    }
}

// -------- MFMA dense: Y = in@Wrel^T (bf16), R = in@Wroot^T + b (bf16) ------
// One wave per 16-node group (2 groups/wave). A-frag: lane holds row (l&15),
// 8 contiguous k at 8*(l>>4) per 32-k step. B-frag: same mapping on W rows
// (consistent k-permutation on both operands cancels vs HW slot order).
// C/D (HW-verified): col = lane&15, row = (lane>>4)*4 + reg.
// NOTE: in_ may alias R (in-place layer-2); each wave reads its rows before
// storing them, and no other wave touches them. No __restrict__ on in_/R.
template<bool BF16IN>
__global__ __launch_bounds__(256) void k_xform_mfma(const void* in_,
                                                    const float* __restrict__ Wrel,
                                                    const float* __restrict__ Wroot,
                                                    const float* __restrict__ bias,
                                                    u16* __restrict__ Y,
                                                    u16* R, int n, int ngroups)
{
    int lane = threadIdx.x & 63;
    int lr = lane & 15;      // A-row / B-row(=out ch) / D-col
    int g  = lane >> 4;      // k-group

    // weight fragments in VGPRs: [mat][n-tile][k-step]
    bf16x8 wf[2][4][2];
    const float* Wm[2] = { Wrel, Wroot };
#pragma unroll
    for (int m = 0; m < 2; ++m)
#pragma unroll
        for (int t = 0; t < 4; ++t)
#pragma unroll
            for (int kt = 0; kt < 2; ++kt) {
                const float* p = Wm[m] + (16 * t + lr) * CH + 32 * kt + 8 * g;
                bf16x8 v;
#pragma unroll
                for (int j = 0; j < 8; ++j) v[j] = (short)f2bf(p[j]);
                wf[m][t][kt] = v;
            }
    float bvt[4];
#pragma unroll
    for (int t = 0; t < 4; ++t) bvt[t] = bias[16 * t + lr];

    int wid = blockIdx.x * 4 + (threadIdx.x >> 6);
#pragma unroll
    for (int gi = 0; gi < 2; ++gi) {
        int grp = wid * 2 + gi;
        if (grp >= ngroups) return;
        int gbase = grp * 16;
        int arow = gbase + lr;
        if (arow >= n) arow = n - 1;

        bf16x8 af[2];
#pragma unroll
        for (int kt = 0; kt < 2; ++kt) {
            if (BF16IN) {
                const u16* hp = (const u16*)in_ + (size_t)arow * CH + kt * 32 + 8 * g;
                af[kt] = *(const bf16x8*)hp;
            } else {
                const float* xp = (const float*)in_ + (size_t)arow * CH + kt * 32 + 8 * g;
                bf16x8 v;
#pragma unroll
                for (int j = 0; j < 8; ++j) v[j] = (short)f2bf(xp[j]);
                af[kt] = v;
            }
        }

        f32x4 z = { 0.f, 0.f, 0.f, 0.f };
        f32x4 aY[4] = { z, z, z, z };
        f32x4 aR[4] = { z, z, z, z };
#pragma unroll
        for (int kt = 0; kt < 2; ++kt)
#pragma unroll
            for (int t = 0; t < 4; ++t) {
                aY[t] = __builtin_amdgcn_mfma_f32_16x16x32_bf16(af[kt], wf[0][t][kt], aY[t], 0, 0, 0);
                aR[t] = __builtin_amdgcn_mfma_f32_16x16x32_bf16(af[kt], wf[1][t][kt], aR[t], 0, 0, 0);
            }

#pragma unroll
        for (int t = 0; t < 4; ++t)
#pragma unroll
            for (int r = 0; r < 4; ++r) {
                int node = gbase + 4 * g + r;
                if (node < n) {
                    Y[(size_t)node * CH + 16 * t + lr] = f2bf(aY[t][r]);
                    R[(size_t)node * CH + 16 * t + lr] = f2bf(aR[t][r] + bvt[t]);
                }
            }
    }
}

// -------- gather v2: 4 independent nodes per wave (one per 16-lane group) --
// 16 lanes x uint2 = full 128B bf16 row -> no cross-lane reduce at all.
// Groups walk contiguous chunks (rowptr e1->e0 reuse). !POOL: in-place
// RO = relu(agg + RO). POOL: group-local running per-graph accumulator,
// 4 scalar atomics/lane on graph change (batch sorted).
template<bool POOL>
__global__ __launch_bounds__(256) void k_gather2(const u16* __restrict__ Y,
                                                 const int* __restrict__ rowptr,
                                                 const int* __restrict__ csr,
                                                 u16* RO,
                                                 const int* __restrict__ batch,
                                                 float* __restrict__ sums,
                                                 int n, int chunk)
{
    int lane = threadIdx.x & 63;
    int sub = lane & 15;
    int grp = lane >> 4;
    int gid = (blockIdx.x * 4 + (threadIdx.x >> 6)) * 4 + grp;
    int nb = gid * chunk;
    if (nb >= n) return;
    int ne = min(nb + chunk, n);
    float4 run = make_float4(0, 0, 0, 0);
    int gcur = -1;
    int e0 = rowptr[nb];
    for (int node = nb; node < ne; ++node) {
        int e1 = rowptr[node + 1];
        float4 accA = make_float4(0, 0, 0, 0), accB = accA;
        int e = e0;
        for (; e + 4 <= e1; e += 4) {
            int s0 = csr[e + 0], s1 = csr[e + 1];
            int s2 = csr[e + 2], s3 = csr[e + 3];
            uint2 p0 = *(const uint2*)(Y + (size_t)s0 * CH + sub * 4);
            uint2 p1 = *(const uint2*)(Y + (size_t)s1 * CH + sub * 4);
            uint2 p2 = *(const uint2*)(Y + (size_t)s2 * CH + sub * 4);
            uint2 p3 = *(const uint2*)(Y + (size_t)s3 * CH + sub * 4);
            bfacc(accA, p0.x, p0.y); bfacc(accB, p1.x, p1.y);
            bfacc(accA, p2.x, p2.y); bfacc(accB, p3.x, p3.y);
        }
        for (; e < e1; ++e) {
            int s = csr[e];
            uint2 p = *(const uint2*)(Y + (size_t)s * CH + sub * 4);
            bfacc(accA, p.x, p.y);
        }
        e0 = e1;
        uint2 pr = *(const uint2*)(RO + (size_t)node * CH + sub * 4);
        float4 r = make_float4(0, 0, 0, 0);
        bfacc(r, pr.x, pr.y);
        f4add(accA, accB);
        float4 h;
        h.x = fmaxf(accA.x + r.x, 0.f); h.y = fmaxf(accA.y + r.y, 0.f);
        h.z = fmaxf(accA.z + r.z, 0.f); h.w = fmaxf(accA.w + r.w, 0.f);
        if (!POOL) {
            uint2 o;
            o.x = (unsigned)f2bf(h.x) | ((unsigned)f2bf(h.y) << 16);
            o.y = (unsigned)f2bf(h.z) | ((unsigned)f2bf(h.w) << 16);
            *(uint2*)(RO + (size_t)node * CH + sub * 4) = o;
        } else {
            int g = batch[node];
            if (g != gcur) {
                if (gcur >= 0) {
                    float* s = sums + gcur * CH + sub * 4;
                    atomicAdd(s + 0, run.x); atomicAdd(s + 1, run.y);
                    atomicAdd(s + 2, run.z); atomicAdd(s + 3, run.w);
                }
                run = make_float4(0, 0, 0, 0);
                gcur = g;
            }
            f4add(run, h);
        }
    }
    if (POOL && gcur >= 0) {
        float* s = sums + gcur * CH + sub * 4;
        atomicAdd(s + 0, run.x); atomicAdd(s + 1, run.y);
        atomicAdd(s + 2, run.z); atomicAdd(s + 3, run.w);
    }
}

// -------- final head --------------------------------------------------------
__global__ void k_final(const float* __restrict__ sums,
                        const int* __restrict__ batch,
                        const float* __restrict__ Wlin,
                        const float* __restrict__ blin,
                        float* __restrict__ out, int n_nodes)
{
    int t = threadIdx.x;
    if (t >= NG * NC) return;
    int g = t / NC, c = t % NC;
    int lo = 0, hi = n_nodes;
    while (lo < hi) { int mid = (lo + hi) >> 1; if (batch[mid] < g) lo = mid + 1; else hi = mid; }
    int lb = lo;
    lo = 0; hi = n_nodes;
    while (lo < hi) { int mid = (lo + hi) >> 1; if (batch[mid] < g + 1) lo = mid + 1; else hi = mid; }
    int cnt = lo - lb;
    float inv = 1.0f / fmaxf((float)cnt, 1.0f);
    float acc = blin[c];
    for (int k = 0; k < CH; ++k)
        acc += sums[g * CH + k] * inv * Wlin[c * CH + k];
    out[g * NC + c] = acc;
}

extern "C" void kernel_launch(void* const* d_in, const int* in_sizes, int n_in,
                              void* d_out, int out_size, void* d_ws, size_t ws_size,
                              hipStream_t stream)
{
    const float* x      = (const float*)d_in[0];
    const int*   ei     = (const int*)d_in[1];
    const int*   batch  = (const int*)d_in[2];
    const float* W1rel  = (const float*)d_in[3];
    const float* W1root = (const float*)d_in[4];
    const float* b1     = (const float*)d_in[5];
    const float* W2rel  = (const float*)d_in[6];
    const float* W2root = (const float*)d_in[7];
    const float* b2     = (const float*)d_in[8];
    const float* Wlin   = (const float*)d_in[9];
    const float* blin   = (const float*)d_in[10];
    float* out = (float*)d_out;

    int n_nodes = in_sizes[0] / CH;
    int n_edges = in_sizes[1] / 2;
    const int* src = ei;
    const int* dst = ei + n_edges;

    int nb  = (n_nodes + BW - 1) >> SHIFT;          // buckets (<=256)
    int cap = n_edges / nb + 2048;                  // per-bucket capacity

    // workspace: Ybf | Rbf(H) | rowptr | csr | bbuf | bcnt | bbase | sums (~40MB)
    u16*   Ybf    = (u16*)d_ws;
    u16*   Rbf    = Ybf + (size_t)n_nodes * CH;
    int*   rowptr = (int*)(Rbf + (size_t)n_nodes * CH);
    int*   csr    = rowptr + (n_nodes + 1);
    int*   bbuf   = csr + n_edges;
    int*   bcnt   = bbuf + (size_t)nb * cap;
    int*   bbase  = bcnt + 256;
    float* sums   = (float*)(bbase + 257);

    // ---- build CSR (dst -> srcs) via bucketed counting sort ----
    hipMemsetAsync(bcnt, 0, 256 * sizeof(int), stream);
    int b1blocks = (n_edges + EPW - 1) / EPW;
    k_bucket<<<b1blocks, 256, 0, stream>>>(src, dst, bcnt, bbuf, nb, cap, n_edges);
    k_bscan<<<1, 256, 0, stream>>>(bcnt, bbase, rowptr, nb, n_nodes, cap);
    k_build<<<nb, 256, 0, stream>>>(bbuf, bcnt, bbase, rowptr, csr, cap, n_nodes);

    int ngroups16 = (n_nodes + 15) / 16;
    int xblocks = (ngroups16 + 7) / 8;              // 4 waves x 2 groups

    // gather grid: 4-node chunks, 4 groups/wave, 4 waves/block
    int chunk = 4;
    int gg = (n_nodes + chunk - 1) / chunk;
    int gblocks = (gg + 15) / 16;

    // ---- layer 1 ----
    k_xform_mfma<false><<<xblocks, 256, 0, stream>>>(x, W1rel, W1root, b1,
                                                     Ybf, Rbf, n_nodes, ngroups16);
    k_gather2<false><<<gblocks, 256, 0, stream>>>(Ybf, rowptr, csr, Rbf,
                                                  batch, sums, n_nodes, chunk);

    // ---- layer 2 ----
    k_xform_mfma<true><<<xblocks, 256, 0, stream>>>(Rbf, W2rel, W2root, b2,
                                                    Ybf, Rbf, n_nodes, ngroups16);
    hipMemsetAsync(sums, 0, NG * CH * sizeof(float), stream);
    k_gather2<true><<<gblocks, 256, 0, stream>>>(Ybf, rowptr, csr, Rbf,
                                                 batch, sums, n_nodes, chunk);

    // ---- head ----
    k_final<<<1, NG * NC, 0, stream>>>(sums, batch, Wlin, blin, out, n_nodes);
}